// Round 9
// baseline (220.617 us; speedup 1.0000x reference)
//
#include <hip/hip_runtime.h>

// MetaBaseline: B,Q,WAY,SHOT,H,W,C = 2,75,5,5,10,10,640; k=5
#define QN    75
#define HWN   100
#define CN    640
#define NSUP  500                      // support descriptors per (b, group)
#define MROWS 7500                     // query patches per batch
#define NQD   (2 * MROWS)              // 15000
#define NSD   5000
#define MT    64                       // rows per workgroup
#define NT    256                      // cols per workgroup (split-N: 2 chunks)
#define BK    64                       // K-chunk (10 iterations)
#define CST   272                      // epilogue C stride (dwords); 272%32==16 -> 2-way scan

typedef __attribute__((ext_vector_type(8))) __bf16 bf16x8;
typedef __attribute__((ext_vector_type(4))) float  f32x4;

// async global->LDS DMA, 16B per lane; LDS dest = wave-uniform base + lane*16
#define GLDS(gp, lp) __builtin_amdgcn_global_load_lds(                        \
    (const __attribute__((address_space(1))) void*)(gp),                      \
    (__attribute__((address_space(3))) void*)(lp), 16, 0, 0)

static __device__ inline unsigned short f2bf(float f) {
    unsigned int u = __float_as_uint(f);
    u += 0x7fffu + ((u >> 16) & 1u);        // RNE
    return (unsigned short)(u >> 16);
}

// ---------------------------------------------------------------------------
// Prep: one wave per descriptor (R6 version), inv-norm, normalized bf16 -> ws.
// ---------------------------------------------------------------------------
__global__ __launch_bounds__(256) void prep_kernel(const float* __restrict__ q,
                                                   const float* __restrict__ s,
                                                   unsigned short* __restrict__ qbf,
                                                   unsigned short* __restrict__ sbf) {
    int wave = (blockIdx.x * 256 + threadIdx.x) >> 6;
    int lane = threadIdx.x & 63;
    if (wave >= NQD + NSD) return;
    const float* src = (wave < NQD) ? (q + (size_t)wave * CN)
                                    : (s + (size_t)(wave - NQD) * CN);
    unsigned short* dst = (wave < NQD) ? (qbf + (size_t)wave * CN)
                                       : (sbf + (size_t)(wave - NQD) * CN);
    float4 v[3];
    float ss = 0.f;
#pragma unroll
    for (int j = 0; j < 3; ++j) {
        int idx4 = lane + 64 * j;
        if (idx4 < CN / 4) {
            v[j] = *(const float4*)(src + idx4 * 4);
            ss = fmaf(v[j].x, v[j].x, ss);
            ss = fmaf(v[j].y, v[j].y, ss);
            ss = fmaf(v[j].z, v[j].z, ss);
            ss = fmaf(v[j].w, v[j].w, ss);
        }
    }
#pragma unroll
    for (int off = 32; off > 0; off >>= 1)
        ss += __shfl_xor(ss, off, 64);
    float inv = rsqrtf(ss);
#pragma unroll
    for (int j = 0; j < 3; ++j) {
        int idx4 = lane + 64 * j;
        if (idx4 < CN / 4) {
            ushort4 o;
            o.x = f2bf(v[j].x * inv);
            o.y = f2bf(v[j].y * inv);
            o.z = f2bf(v[j].z * inv);
            o.w = f2bf(v[j].w * inv);
            *(ushort4*)(dst + idx4 * 4) = o;
        }
    }
}

// ---------------------------------------------------------------------------
// MFMA GEMM (64x256 tile) + per-row top-5 partials.  R9: A-fragments loaded
// DIRECTLY global->VGPR (no A LDS staging) — R8 pipe budget showed the LDS
// read pipe is the top per-CU consumer (A read redundantly by all 4 col-
// waves); per-iter A working set (16 KB) is L1-resident. B stays on the
// async-DMA LDS path with the (r&7) granule swizzle (2-way, free).
// grid = (118 M, 2 N-chunks, 10 (b,g)), block = 256 (4 waves).
// Occupancy is pinned at ~12 waves/CU regardless of config (R7/R8 evidence),
// so spending ~32 VGPR on A-frags costs nothing.
// ---------------------------------------------------------------------------
__global__ __launch_bounds__(256, 3) void mfma_kernel(const unsigned short* __restrict__ qbf,
                                                      const unsigned short* __restrict__ sbf,
                                                      float* __restrict__ part) {
    __shared__ __align__(16) char smem[32768];             // B 32 KB (Cst reuses)
    unsigned short* Blds = (unsigned short*)smem;          // [256 cols][64 k] swizzled
    float*          Cst  = (float*)smem;                   // epilogue [16][CST] = 17.4 KB

    const int t    = threadIdx.x;
    const int lane = t & 63;
    const int wid  = t >> 6;
    const int bg   = blockIdx.z;           // b*5+g
    const int b    = bg / 5;
    const int g    = bg % 5;
    const int nc   = blockIdx.y;           // N-chunk
    const int r0   = blockIdx.x * MT;
    const int c0   = nc * NT;

    const unsigned short* qptr = qbf + (size_t)b * MROWS * CN;              // uniform
    const unsigned short* sptr = sbf + (size_t)(b * 25 + g * 5) * HWN * CN; // uniform

    f32x4 acc[4][4];
#pragma unroll
    for (int mt = 0; mt < 4; ++mt)
#pragma unroll
        for (int nt = 0; nt < 4; ++nt)
            acc[mt][nt] = (f32x4)0.f;

    const int q_ = lane >> 4;      // k-quad
    const int lr = lane & 15;      // row/col within 16x16 tile
    const int sw = lr & 7;         // B read-side swizzle term

    // A: per-lane global base pointers, one per mt (row = r0 + mt*16 + lr)
    const unsigned short* aptr[4];
#pragma unroll
    for (int mt = 0; mt < 4; ++mt) {
        int row = r0 + mt * 16 + lr;
        if (row > MROWS - 1) row = MROWS - 1;
        aptr[mt] = qptr + (size_t)row * CN + q_ * 8;
    }

    // B staging (async DMA): per-lane source offset, wave-uniform LDS dest
    const int lx   = lane >> 3;          // 0..7: col within 8-col chunk
    const int ls   = lane & 7;           // dest slot (lane-fixed)
    const int gsrc = ls ^ lx;            // source granule for this lane
    int boff[8];
#pragma unroll
    for (int c = 0; c < 8; ++c) {
        int col = c0 + wid * 64 + c * 8 + lx;
        if (col > NSUP - 1) col = NSUP - 1;
        boff[c] = col * CN + gsrc * 8;
    }
    char* bldst = smem + wid * 8192;

    for (int k0 = 0; k0 < CN; k0 += BK) {
        __syncthreads();                      // prior ds/Cst readers done
#pragma unroll
        for (int c = 0; c < 8; ++c)
            GLDS(sptr + boff[c] + k0, bldst + c * 1024);
        // A frags for both ks halves, global->VGPR (drained by same barrier)
        bf16x8 af[2][4];
#pragma unroll
        for (int ks = 0; ks < 2; ++ks)
#pragma unroll
            for (int mt = 0; mt < 4; ++mt)
                af[ks][mt] = *(const bf16x8*)(aptr[mt] + k0 + ks * 32);
        __syncthreads();                      // vmcnt(0) drain -> B landed

#pragma unroll
        for (int ks = 0; ks < 2; ++ks) {
            const int sl = ((ks * 4 + q_) ^ sw) * 8;
#pragma unroll
            for (int nt = 0; nt < 4; ++nt) {
                bf16x8 bfr = *(const bf16x8*)(Blds + (wid * 64 + nt * 16 + lr) * 64 + sl);
#pragma unroll
                for (int mt = 0; mt < 4; ++mt)
                    acc[mt][nt] = __builtin_amdgcn_mfma_f32_16x16x32_bf16(af[ks][mt], bfr, acc[mt][nt], 0, 0, 0);
            }
        }
    }

    // -------- epilogue: per-16-row chunks, sorted top-5 -> partials --------
    // FULLY UNROLLED over mt (runtime acc[] index -> scratch spill; see R2).
    const int erow = t >> 4;        // 0..15
    const int es   = t & 15;        // 16 scanners per row
#define CE(a, b) { float hi_ = fmaxf(a, b), lo_ = fminf(a, b); a = hi_; b = lo_; }
#pragma unroll
    for (int mt = 0; mt < 4; ++mt) {
        __syncthreads();
#pragma unroll
        for (int nt = 0; nt < 4; ++nt)
#pragma unroll
            for (int e = 0; e < 4; ++e)
                Cst[(q_ * 4 + e) * CST + wid * 64 + nt * 16 + lr] = acc[mt][nt][e];
        __syncthreads();

        float t0 = -3.4e38f, t1 = -3.4e38f, t2 = -3.4e38f, t3 = -3.4e38f, t4 = -3.4e38f;
#pragma unroll
        for (int i = 0; i < 16; ++i) {
            int col = es + 16 * i;
            float v = (c0 + col < NSUP) ? Cst[erow * CST + col] : -3.4e38f;
            float hi;
            hi = fmaxf(t0, v); v = fminf(t0, v); t0 = hi;
            hi = fmaxf(t1, v); v = fminf(t1, v); t1 = hi;
            hi = fmaxf(t2, v); v = fminf(t2, v); t2 = hi;
            hi = fmaxf(t3, v); v = fminf(t3, v); t3 = hi;
            hi = fmaxf(t4, v); v = fminf(t4, v); t4 = hi;
        }
#pragma unroll
        for (int d = 1; d < 16; d <<= 1) {
            float b0 = __shfl_xor(t0, d, 64);
            float b1 = __shfl_xor(t1, d, 64);
            float b2 = __shfl_xor(t2, d, 64);
            float b3 = __shfl_xor(t3, d, 64);
            float b4 = __shfl_xor(t4, d, 64);
            t0 = fmaxf(t0, b4); t1 = fmaxf(t1, b3); t2 = fmaxf(t2, b2);
            t3 = fmaxf(t3, b1); t4 = fmaxf(t4, b0);
            CE(t0, t1); CE(t2, t3);
            CE(t1, t2); CE(t3, t4);
            CE(t0, t1); CE(t2, t3);
            CE(t1, t2); CE(t3, t4);
            CE(t0, t1); CE(t2, t3);
        }
        if (es == 0) {
            int patch = r0 + mt * 16 + erow;
            if (patch < MROWS) {
                float* pp = part + ((size_t)(bg * MROWS + patch) * 2 + nc) * 5;
                pp[0] = t0; pp[1] = t1; pp[2] = t2; pp[3] = t3; pp[4] = t4;
            }
        }
    }
#undef CE
}

// ---------------------------------------------------------------------------
// Merge: one wave per (b,qi,g) = 750 waves. Top-5 of the union of the two
// sorted per-chunk top-5s, mean, wave-reduce over 100 patches, direct store.
// ---------------------------------------------------------------------------
__global__ __launch_bounds__(256) void merge_kernel(const float* __restrict__ part,
                                                    float* __restrict__ out) {
    int w    = (blockIdx.x * 256 + threadIdx.x) >> 6;
    int lane = threadIdx.x & 63;
    if (w >= 750) return;
    int b  = w / 375, r = w % 375;
    int qi = r / 5,   g = r % 5;
    int bg = b * 5 + g;

    float sum = 0.f;
    for (int p = lane; p < HWN; p += 64) {
        int row = qi * HWN + p;
        const float* pp = part + (size_t)(bg * MROWS + row) * 10;
        float t0 = -3.4e38f, t1 = -3.4e38f, t2 = -3.4e38f, t3 = -3.4e38f, t4 = -3.4e38f;
#pragma unroll
        for (int j = 0; j < 10; ++j) {
            float v = pp[j], hi;
            hi = fmaxf(t0, v); v = fminf(t0, v); t0 = hi;
            hi = fmaxf(t1, v); v = fminf(t1, v); t1 = hi;
            hi = fmaxf(t2, v); v = fminf(t2, v); t2 = hi;
            hi = fmaxf(t3, v); v = fminf(t3, v); t3 = hi;
            hi = fmaxf(t4, v); v = fminf(t4, v); t4 = hi;
        }
        sum += (t0 + t1 + t2 + t3 + t4) * 0.2f;
    }
#pragma unroll
    for (int off = 32; off > 0; off >>= 1)
        sum += __shfl_xor(sum, off, 64);
    if (lane == 0) out[w] = sum;        // out[(b*75+qi)*5+g] == out[w]
}

extern "C" void kernel_launch(void* const* d_in, const int* in_sizes, int n_in,
                              void* d_out, int out_size, void* d_ws, size_t ws_size,
                              hipStream_t stream) {
    const float* in1 = (const float*)d_in[0];
    const float* in2 = (const float*)d_in[1];
    float* out = (float*)d_out;

    unsigned short* qbf  = (unsigned short*)d_ws;            // 15000*640 bf16 = 19.2 MB
    unsigned short* sbf  = qbf + (size_t)NQD * CN;           //  5000*640 bf16 =  6.4 MB
    float*          part = (float*)(sbf + (size_t)NSD * CN); // 10*7500*2*5 fp32 = 3 MB

    prep_kernel<<<dim3((NQD + NSD) / 4), 256, 0, stream>>>(in1, in2, qbf, sbf);
    dim3 grid((MROWS + MT - 1) / MT, 2, 10);   // (118, 2, 10) = 2360 blocks
    mfma_kernel<<<grid, 256, 0, stream>>>(qbf, sbf, part);
    merge_kernel<<<dim3(188), 256, 0, stream>>>(part, out);   // 750 waves
}

// Round 10
// 176.941 us; speedup vs baseline: 1.2468x; 1.2468x over previous
//
#include <hip/hip_runtime.h>

// MetaBaseline: B,Q,WAY,SHOT,H,W,C = 2,75,5,5,10,10,640; k=5
#define QN    75
#define HWN   100
#define CN    640
#define NSUP  500                      // support descriptors per (b, group)
#define MROWS 7500                     // query patches per batch
#define NQD   (2 * MROWS)              // 15000
#define NSD   5000
#define NDESC (NQD + NSD)              // 20000
#define MT    128                      // rows per workgroup
#define NT    256                      // cols per workgroup (split-N: 2 chunks)
#define BK    64                       // K-chunk (10 iterations)
#define CST   272                      // epilogue C stride (dwords); 272%32==16 -> 2-way scan

typedef __attribute__((ext_vector_type(8))) __bf16 bf16x8;
typedef __attribute__((ext_vector_type(4))) float  f32x4;

// async global->LDS DMA, 16B per lane; LDS dest = wave-uniform base + lane*16
#define GLDS(gp, lp) __builtin_amdgcn_global_load_lds(                        \
    (const __attribute__((address_space(1))) void*)(gp),                      \
    (__attribute__((address_space(3))) void*)(lp), 16, 0, 0)

static __device__ inline unsigned short f2bf(float f) {
    unsigned int u = __float_as_uint(f);
    u += 0x7fffu + ((u >> 16) & 1u);        // RNE
    return (unsigned short)(u >> 16);
}

// ---------------------------------------------------------------------------
// R10 prep split (R3-R8 fused prep implicated in a ~70 us fixed cost vs a
// ~16 us memory floor). Stage 1: norms only — read fp32, reduce, write 1
// float per descriptor. No value caching, minimal registers.
// ---------------------------------------------------------------------------
__global__ __launch_bounds__(256) void norm_kernel(const float* __restrict__ q,
                                                   const float* __restrict__ s,
                                                   float* __restrict__ invs) {
    int wave = (blockIdx.x * 256 + threadIdx.x) >> 6;
    int lane = threadIdx.x & 63;
    if (wave >= NDESC) return;
    const float* src = (wave < NQD) ? (q + (size_t)wave * CN)
                                    : (s + (size_t)(wave - NQD) * CN);
    float ss = 0.f;
#pragma unroll
    for (int j = 0; j < 2; ++j) {            // 128 float4s: lanes 0..63 x2
        float4 v = *(const float4*)(src + (lane + 64 * j) * 4);
        ss = fmaf(v.x, v.x, ss);
        ss = fmaf(v.y, v.y, ss);
        ss = fmaf(v.z, v.z, ss);
        ss = fmaf(v.w, v.w, ss);
    }
    if (lane < 32) {                         // tail: 32 float4s
        float4 v = *(const float4*)(src + (lane + 128) * 4);
        ss = fmaf(v.x, v.x, ss);
        ss = fmaf(v.y, v.y, ss);
        ss = fmaf(v.z, v.z, ss);
        ss = fmaf(v.w, v.w, ss);
    }
#pragma unroll
    for (int off = 32; off > 0; off >>= 1)
        ss += __shfl_xor(ss, off, 64);
    if (lane == 0) invs[wave] = rsqrtf(ss);
}

// ---------------------------------------------------------------------------
// Stage 2: pure streaming scale+convert. Each thread: 8 consecutive floats
// (32 B read) * inv (L1-hot scalar) -> 8 bf16 (16 B write). 1.6M threads,
// no sync, no divergence, no serial chains.
// ---------------------------------------------------------------------------
__global__ __launch_bounds__(256) void convert_kernel(const float* __restrict__ q,
                                                      const float* __restrict__ s,
                                                      const float* __restrict__ invs,
                                                      unsigned short* __restrict__ qbf,
                                                      unsigned short* __restrict__ sbf) {
    int gid = blockIdx.x * 256 + threadIdx.x;     // 0 .. 1,599,999
    if (gid >= NDESC * (CN / 8)) return;
    int desc = gid / (CN / 8);
    int sub  = gid - desc * (CN / 8);             // 0..79
    const float* src = (desc < NQD) ? (q + (size_t)desc * CN)
                                    : (s + (size_t)(desc - NQD) * CN);
    unsigned short* dst = (desc < NQD) ? (qbf + (size_t)desc * CN)
                                       : (sbf + (size_t)(desc - NQD) * CN);
    float inv = invs[desc];
    float4 v0 = *(const float4*)(src + sub * 8);
    float4 v1 = *(const float4*)(src + sub * 8 + 4);
    union { ushort4 u4[2]; uint4 u128; } o;
    o.u4[0].x = f2bf(v0.x * inv); o.u4[0].y = f2bf(v0.y * inv);
    o.u4[0].z = f2bf(v0.z * inv); o.u4[0].w = f2bf(v0.w * inv);
    o.u4[1].x = f2bf(v1.x * inv); o.u4[1].y = f2bf(v1.y * inv);
    o.u4[1].z = f2bf(v1.z * inv); o.u4[1].w = f2bf(v1.w * inv);
    *(uint4*)(dst + sub * 8) = o.u128;
}

// ---------------------------------------------------------------------------
// MFMA GEMM (128x256 tile, 512 threads = 8 waves) + per-row top-5 partials.
// R8 config verbatim — best measured (77.5 us, MfmaUtil 25.6%). R9's
// global-A variant regressed to 138 us (per-lane A-load latency entered the
// per-iteration critical path); reverted.
// LDS swizzle: slot s of row r holds source granule s^(r&7); frag reads use
// slot (ks*4+q_)^(lr&7) -> 2-way conflicts (free, m136).
// ---------------------------------------------------------------------------
__global__ __launch_bounds__(512, 4) void mfma_kernel(const unsigned short* __restrict__ qbf,
                                                      const unsigned short* __restrict__ sbf,
                                                      float* __restrict__ part) {
    __shared__ __align__(16) char smem[49152];             // A 16 KB + B 32 KB
    unsigned short* Alds = (unsigned short*)smem;          // [128 rows][64 k] swizzled
    unsigned short* Blds = (unsigned short*)(smem + 16384);// [256 cols][64 k] swizzled
    float*          Cst  = (float*)smem;                   // epilogue [32][CST] = 34.8 KB

    const int t    = threadIdx.x;
    const int lane = t & 63;
    const int wid  = t >> 6;               // 0..7
    const int h    = wid >> 2;             // row half (0/1)
    const int colq = wid & 3;              // col quarter (0..3)
    const int bg   = blockIdx.z;           // b*5+g
    const int b    = bg / 5;
    const int g    = bg % 5;
    const int nc   = blockIdx.y;           // N-chunk
    const int r0   = blockIdx.x * MT;
    const int c0   = nc * NT;

    const unsigned short* qptr = qbf + (size_t)b * MROWS * CN;              // uniform
    const unsigned short* sptr = sbf + (size_t)(b * 25 + g * 5) * HWN * CN; // uniform

    f32x4 acc[4][4];
#pragma unroll
    for (int mt = 0; mt < 4; ++mt)
#pragma unroll
        for (int nt = 0; nt < 4; ++nt)
            acc[mt][nt] = (f32x4)0.f;

    // ---- async staging setup (per-lane source offset, uniform LDS dest) ----
    const int lx   = lane >> 3;          // 0..7: row/col within 8-row chunk
    const int ls   = lane & 7;           // dest slot (lane-fixed)
    const int gsrc = ls ^ lx;            // source granule for this lane

    // A: wave w stages rows [w*16, +16) as 2 chunks of 8 rows
    int ar0 = r0 + wid * 16 + lx;       if (ar0 > MROWS - 1) ar0 = MROWS - 1;
    int ar1 = r0 + wid * 16 + 8 + lx;   if (ar1 > MROWS - 1) ar1 = MROWS - 1;
    const int aoff0 = ar0 * CN + gsrc * 8;
    const int aoff1 = ar1 * CN + gsrc * 8;
    char* aldst = smem + wid * 2048;

    // B: wave w stages cols [c0 + w*32, +32) as 4 chunks of 8 cols (clamped)
    int boff[4];
#pragma unroll
    for (int c = 0; c < 4; ++c) {
        int col = c0 + wid * 32 + c * 8 + lx;
        if (col > NSUP - 1) col = NSUP - 1;
        boff[c] = col * CN + gsrc * 8;
    }
    char* bldst = smem + 16384 + wid * 4096;

    const int q_ = lane >> 4;      // k-quad
    const int lr = lane & 15;      // row/col within 16x16 tile
    const int sw = lr & 7;         // read-side swizzle term

    for (int k0 = 0; k0 < CN; k0 += BK) {
        __syncthreads();                      // prior ds_reads done
        GLDS(qptr + aoff0 + k0, aldst);
        GLDS(qptr + aoff1 + k0, aldst + 1024);
#pragma unroll
        for (int c = 0; c < 4; ++c)
            GLDS(sptr + boff[c] + k0, bldst + c * 1024);
        __syncthreads();                      // vmcnt(0) drain -> tiles landed

#pragma unroll
        for (int ks = 0; ks < 2; ++ks) {
            const int sl = ((ks * 4 + q_) ^ sw) * 8;
            bf16x8 af[4];
#pragma unroll
            for (int mt = 0; mt < 4; ++mt)
                af[mt] = *(const bf16x8*)(Alds + (h * 64 + mt * 16 + lr) * 64 + sl);
#pragma unroll
            for (int nt = 0; nt < 4; ++nt) {
                bf16x8 bfr = *(const bf16x8*)(Blds + (colq * 64 + nt * 16 + lr) * 64 + sl);
#pragma unroll
                for (int mt = 0; mt < 4; ++mt)
                    acc[mt][nt] = __builtin_amdgcn_mfma_f32_16x16x32_bf16(af[mt], bfr, acc[mt][nt], 0, 0, 0);
            }
        }
    }

    // -------- epilogue: per-mt, 32 C-rows (both halves) via LDS -----------
    // FULLY UNROLLED over mt (runtime acc[] index -> scratch spill; see R2).
    const int erow = t >> 4;        // 0..31 (Cst row)
    const int es   = t & 15;        // 16 scanners per row (within one wave)
#define CE(a, b) { float hi_ = fmaxf(a, b), lo_ = fminf(a, b); a = hi_; b = lo_; }
#pragma unroll
    for (int mt = 0; mt < 4; ++mt) {
        __syncthreads();
#pragma unroll
        for (int nt = 0; nt < 4; ++nt)
#pragma unroll
            for (int e = 0; e < 4; ++e)
                Cst[(h * 16 + q_ * 4 + e) * CST + colq * 64 + nt * 16 + lr] = acc[mt][nt][e];
        __syncthreads();

        float t0 = -3.4e38f, t1 = -3.4e38f, t2 = -3.4e38f, t3 = -3.4e38f, t4 = -3.4e38f;
#pragma unroll
        for (int i = 0; i < 16; ++i) {
            int col = es + 16 * i;
            float v = (c0 + col < NSUP) ? Cst[erow * CST + col] : -3.4e38f;
            float hi;
            hi = fmaxf(t0, v); v = fminf(t0, v); t0 = hi;
            hi = fmaxf(t1, v); v = fminf(t1, v); t1 = hi;
            hi = fmaxf(t2, v); v = fminf(t2, v); t2 = hi;
            hi = fmaxf(t3, v); v = fminf(t3, v); t3 = hi;
            hi = fmaxf(t4, v); v = fminf(t4, v); t4 = hi;
        }
#pragma unroll
        for (int d = 1; d < 16; d <<= 1) {
            float b0 = __shfl_xor(t0, d, 64);
            float b1 = __shfl_xor(t1, d, 64);
            float b2 = __shfl_xor(t2, d, 64);
            float b3 = __shfl_xor(t3, d, 64);
            float b4 = __shfl_xor(t4, d, 64);
            t0 = fmaxf(t0, b4); t1 = fmaxf(t1, b3); t2 = fmaxf(t2, b2);
            t3 = fmaxf(t3, b1); t4 = fmaxf(t4, b0);
            CE(t0, t1); CE(t2, t3);
            CE(t1, t2); CE(t3, t4);
            CE(t0, t1); CE(t2, t3);
            CE(t1, t2); CE(t3, t4);
            CE(t0, t1); CE(t2, t3);
        }
        if (es == 0) {
            // Cst row erow = eh*16 + crow maps to patch r0 + eh*64 + mt*16 + crow
            int patch = r0 + (erow >> 4) * 64 + mt * 16 + (erow & 15);
            if (patch < MROWS) {
                float* pp = part + ((size_t)(bg * MROWS + patch) * 2 + nc) * 5;
                pp[0] = t0; pp[1] = t1; pp[2] = t2; pp[3] = t3; pp[4] = t4;
            }
        }
    }
#undef CE
}

// ---------------------------------------------------------------------------
// Merge: one wave per (b,qi,g) = 750 waves. Top-5 of the union of the two
// sorted per-chunk top-5s, mean, wave-reduce over 100 patches, direct store.
// ---------------------------------------------------------------------------
__global__ __launch_bounds__(256) void merge_kernel(const float* __restrict__ part,
                                                    float* __restrict__ out) {
    int w    = (blockIdx.x * 256 + threadIdx.x) >> 6;
    int lane = threadIdx.x & 63;
    if (w >= 750) return;
    int b  = w / 375, r = w % 375;
    int qi = r / 5,   g = r % 5;
    int bg = b * 5 + g;

    float sum = 0.f;
    for (int p = lane; p < HWN; p += 64) {
        int row = qi * HWN + p;
        const float* pp = part + (size_t)(bg * MROWS + row) * 10;
        float t0 = -3.4e38f, t1 = -3.4e38f, t2 = -3.4e38f, t3 = -3.4e38f, t4 = -3.4e38f;
#pragma unroll
        for (int j = 0; j < 10; ++j) {
            float v = pp[j], hi;
            hi = fmaxf(t0, v); v = fminf(t0, v); t0 = hi;
            hi = fmaxf(t1, v); v = fminf(t1, v); t1 = hi;
            hi = fmaxf(t2, v); v = fminf(t2, v); t2 = hi;
            hi = fmaxf(t3, v); v = fminf(t3, v); t3 = hi;
            hi = fmaxf(t4, v); v = fminf(t4, v); t4 = hi;
        }
        sum += (t0 + t1 + t2 + t3 + t4) * 0.2f;
    }
#pragma unroll
    for (int off = 32; off > 0; off >>= 1)
        sum += __shfl_xor(sum, off, 64);
    if (lane == 0) out[w] = sum;        // out[(b*75+qi)*5+g] == out[w]
}

extern "C" void kernel_launch(void* const* d_in, const int* in_sizes, int n_in,
                              void* d_out, int out_size, void* d_ws, size_t ws_size,
                              hipStream_t stream) {
    const float* in1 = (const float*)d_in[0];
    const float* in2 = (const float*)d_in[1];
    float* out = (float*)d_out;

    unsigned short* qbf  = (unsigned short*)d_ws;            // 15000*640 bf16 = 19.2 MB
    unsigned short* sbf  = qbf + (size_t)NQD * CN;           //  5000*640 bf16 =  6.4 MB
    float*          part = (float*)(sbf + (size_t)NSD * CN); // 750000 fp32 = 3 MB
    float*          invs = part + 750000;                    // 20000 fp32

    norm_kernel<<<dim3(NDESC / 4), 256, 0, stream>>>(in1, in2, invs);
    convert_kernel<<<dim3((NDESC * (CN / 8) + 255) / 256), 256, 0, stream>>>(in1, in2, invs, qbf, sbf);
    dim3 grid((MROWS + MT - 1) / MT, 2, 10);   // (59, 2, 10) = 1180 blocks
    mfma_kernel<<<grid, 512, 0, stream>>>(qbf, sbf, part);
    merge_kernel<<<dim3(188), 256, 0, stream>>>(part, out);   // 750 waves
}

// Round 11
// 160.213 us; speedup vs baseline: 1.3770x; 1.1044x over previous
//
#include <hip/hip_runtime.h>

// MetaBaseline: B,Q,WAY,SHOT,H,W,C = 2,75,5,5,10,10,640; k=5
#define QN    75
#define HWN   100
#define CN    640
#define NSUP  500                      // support descriptors per (b, group)
#define MROWS 7500                     // query patches per batch
#define NQD   (2 * MROWS)              // 15000
#define NSD   5000
#define NDESC (NQD + NSD)              // 20000
#define MT    128                      // rows per workgroup
#define NT    256                      // cols per workgroup (split-N: 2 chunks)
#define BK    64                       // K-chunk (10 iterations)
#define CST   272                      // epilogue C stride (dwords); 272%32==16 -> 2-way scan

typedef __attribute__((ext_vector_type(8))) __bf16 bf16x8;
typedef __attribute__((ext_vector_type(4))) float  f32x4;

// async global->LDS DMA, 16B per lane; LDS dest = wave-uniform base + lane*16
#define GLDS(gp, lp) __builtin_amdgcn_global_load_lds(                        \
    (const __attribute__((address_space(1))) void*)(gp),                      \
    (__attribute__((address_space(3))) void*)(lp), 16, 0, 0)

static __device__ inline unsigned short f2bf(float f) {
    unsigned int u = __float_as_uint(f);
    u += 0x7fffu + ((u >> 16) & 1u);        // RNE
    return (unsigned short)(u >> 16);
}

// ---------------------------------------------------------------------------
// Prep (fused, R6 version — R10's norm/convert split regressed ~10 us by
// re-reading the fp32 inputs): one wave per descriptor, inv-norm, write
// normalized bf16 to ws.
// ---------------------------------------------------------------------------
__global__ __launch_bounds__(256) void prep_kernel(const float* __restrict__ q,
                                                   const float* __restrict__ s,
                                                   unsigned short* __restrict__ qbf,
                                                   unsigned short* __restrict__ sbf) {
    int wave = (blockIdx.x * 256 + threadIdx.x) >> 6;
    int lane = threadIdx.x & 63;
    if (wave >= NDESC) return;
    const float* src = (wave < NQD) ? (q + (size_t)wave * CN)
                                    : (s + (size_t)(wave - NQD) * CN);
    unsigned short* dst = (wave < NQD) ? (qbf + (size_t)wave * CN)
                                       : (sbf + (size_t)(wave - NQD) * CN);
    float4 v[3];
    float ss = 0.f;
#pragma unroll
    for (int j = 0; j < 3; ++j) {
        int idx4 = lane + 64 * j;
        if (idx4 < CN / 4) {
            v[j] = *(const float4*)(src + idx4 * 4);
            ss = fmaf(v[j].x, v[j].x, ss);
            ss = fmaf(v[j].y, v[j].y, ss);
            ss = fmaf(v[j].z, v[j].z, ss);
            ss = fmaf(v[j].w, v[j].w, ss);
        }
    }
#pragma unroll
    for (int off = 32; off > 0; off >>= 1)
        ss += __shfl_xor(ss, off, 64);
    float inv = rsqrtf(ss);
#pragma unroll
    for (int j = 0; j < 3; ++j) {
        int idx4 = lane + 64 * j;
        if (idx4 < CN / 4) {
            ushort4 o;
            o.x = f2bf(v[j].x * inv);
            o.y = f2bf(v[j].y * inv);
            o.z = f2bf(v[j].z * inv);
            o.w = f2bf(v[j].w * inv);
            *(ushort4*)(dst + idx4 * 4) = o;
        }
    }
}

// ---------------------------------------------------------------------------
// MFMA GEMM (128x256 tile, 512 threads = 8 waves) + per-row top-5 partials.
// R11: XCD-clustered work remap. blockIdx.x & 7 ~ XCD (consecutive blocks
// round-robin XCDs). XCD gets (batch b = xcd>>2 ... wait: 2 batches x 4
// M-quarters): per-XCD L2 footprint A-quarter 2.4 MB + B 3.2 MB = 5.6 MB
// (vs ~26 MB un-clustered -> FETCH_SIZE was 118 MB = 4.6x the 25.6 MB
// working set; every L2 miss inflates the per-iter DMA drain latency).
// Within XCD: works ordered (g, nc, mb) so in-flight footprint ~3.7 MB < 4MB.
// Compute core identical to R8 (best measured: 77.5 us, MfmaUtil 25.6%).
// ---------------------------------------------------------------------------
__global__ __launch_bounds__(512, 4) void mfma_kernel(const unsigned short* __restrict__ qbf,
                                                      const unsigned short* __restrict__ sbf,
                                                      float* __restrict__ part) {
    // ---- work decode: grid = 1200 1-D blocks ----
    const int xcd = blockIdx.x & 7;
    const int idx = blockIdx.x >> 3;          // 0..149
    const int b   = xcd >> 2;                 // batch (0/1)
    const int mbq = xcd & 3;                  // M quarter
    const int mbsz = (mbq < 3) ? 15 : 14;     // quarter sizes: 15,15,15,14 (=59)
    if (idx >= 10 * mbsz) return;             // block-uniform early exit
    const int g  = idx / (2 * mbsz);
    const int r_ = idx % (2 * mbsz);
    const int nc = r_ / mbsz;
    const int mb = mbq * 15 + (r_ % mbsz);    // 0..58
    const int bg = b * 5 + g;
    const int r0 = mb * MT;
    const int c0 = nc * NT;

    __shared__ __align__(16) char smem[49152];             // A 16 KB + B 32 KB
    unsigned short* Alds = (unsigned short*)smem;          // [128 rows][64 k] swizzled
    unsigned short* Blds = (unsigned short*)(smem + 16384);// [256 cols][64 k] swizzled
    float*          Cst  = (float*)smem;                   // epilogue [32][CST] = 34.8 KB

    const int t    = threadIdx.x;
    const int lane = t & 63;
    const int wid  = t >> 6;               // 0..7
    const int h    = wid >> 2;             // row half (0/1)
    const int colq = wid & 3;              // col quarter (0..3)

    const unsigned short* qptr = qbf + (size_t)b * MROWS * CN;              // uniform
    const unsigned short* sptr = sbf + (size_t)(b * 25 + g * 5) * HWN * CN; // uniform

    f32x4 acc[4][4];
#pragma unroll
    for (int mt = 0; mt < 4; ++mt)
#pragma unroll
        for (int nt = 0; nt < 4; ++nt)
            acc[mt][nt] = (f32x4)0.f;

    // ---- async staging setup (per-lane source offset, uniform LDS dest) ----
    const int lx   = lane >> 3;          // 0..7: row/col within 8-row chunk
    const int ls   = lane & 7;           // dest slot (lane-fixed)
    const int gsrc = ls ^ lx;            // source granule for this lane

    // A: wave w stages rows [w*16, +16) as 2 chunks of 8 rows
    int ar0 = r0 + wid * 16 + lx;       if (ar0 > MROWS - 1) ar0 = MROWS - 1;
    int ar1 = r0 + wid * 16 + 8 + lx;   if (ar1 > MROWS - 1) ar1 = MROWS - 1;
    const int aoff0 = ar0 * CN + gsrc * 8;
    const int aoff1 = ar1 * CN + gsrc * 8;
    char* aldst = smem + wid * 2048;

    // B: wave w stages cols [c0 + w*32, +32) as 4 chunks of 8 cols (clamped)
    int boff[4];
#pragma unroll
    for (int c = 0; c < 4; ++c) {
        int col = c0 + wid * 32 + c * 8 + lx;
        if (col > NSUP - 1) col = NSUP - 1;
        boff[c] = col * CN + gsrc * 8;
    }
    char* bldst = smem + 16384 + wid * 4096;

    const int q_ = lane >> 4;      // k-quad
    const int lr = lane & 15;      // row/col within 16x16 tile
    const int sw = lr & 7;         // read-side swizzle term

    for (int k0 = 0; k0 < CN; k0 += BK) {
        __syncthreads();                      // prior ds_reads done
        GLDS(qptr + aoff0 + k0, aldst);
        GLDS(qptr + aoff1 + k0, aldst + 1024);
#pragma unroll
        for (int c = 0; c < 4; ++c)
            GLDS(sptr + boff[c] + k0, bldst + c * 1024);
        __syncthreads();                      // vmcnt(0) drain -> tiles landed

#pragma unroll
        for (int ks = 0; ks < 2; ++ks) {
            const int sl = ((ks * 4 + q_) ^ sw) * 8;
            bf16x8 af[4];
#pragma unroll
            for (int mt = 0; mt < 4; ++mt)
                af[mt] = *(const bf16x8*)(Alds + (h * 64 + mt * 16 + lr) * 64 + sl);
#pragma unroll
            for (int nt = 0; nt < 4; ++nt) {
                bf16x8 bfr = *(const bf16x8*)(Blds + (colq * 64 + nt * 16 + lr) * 64 + sl);
#pragma unroll
                for (int mt = 0; mt < 4; ++mt)
                    acc[mt][nt] = __builtin_amdgcn_mfma_f32_16x16x32_bf16(af[mt], bfr, acc[mt][nt], 0, 0, 0);
            }
        }
    }

    // -------- epilogue: per-mt, 32 C-rows (both halves) via LDS -----------
    // FULLY UNROLLED over mt (runtime acc[] index -> scratch spill; see R2).
    const int erow = t >> 4;        // 0..31 (Cst row)
    const int es   = t & 15;        // 16 scanners per row (within one wave)
#define CE(a, b) { float hi_ = fmaxf(a, b), lo_ = fminf(a, b); a = hi_; b = lo_; }
#pragma unroll
    for (int mt = 0; mt < 4; ++mt) {
        __syncthreads();
#pragma unroll
        for (int nt = 0; nt < 4; ++nt)
#pragma unroll
            for (int e = 0; e < 4; ++e)
                Cst[(h * 16 + q_ * 4 + e) * CST + colq * 64 + nt * 16 + lr] = acc[mt][nt][e];
        __syncthreads();

        float t0 = -3.4e38f, t1 = -3.4e38f, t2 = -3.4e38f, t3 = -3.4e38f, t4 = -3.4e38f;
#pragma unroll
        for (int i = 0; i < 16; ++i) {
            int col = es + 16 * i;
            float v = (c0 + col < NSUP) ? Cst[erow * CST + col] : -3.4e38f;
            float hi;
            hi = fmaxf(t0, v); v = fminf(t0, v); t0 = hi;
            hi = fmaxf(t1, v); v = fminf(t1, v); t1 = hi;
            hi = fmaxf(t2, v); v = fminf(t2, v); t2 = hi;
            hi = fmaxf(t3, v); v = fminf(t3, v); t3 = hi;
            hi = fmaxf(t4, v); v = fminf(t4, v); t4 = hi;
        }
#pragma unroll
        for (int d = 1; d < 16; d <<= 1) {
            float b0 = __shfl_xor(t0, d, 64);
            float b1 = __shfl_xor(t1, d, 64);
            float b2 = __shfl_xor(t2, d, 64);
            float b3 = __shfl_xor(t3, d, 64);
            float b4 = __shfl_xor(t4, d, 64);
            t0 = fmaxf(t0, b4); t1 = fmaxf(t1, b3); t2 = fmaxf(t2, b2);
            t3 = fmaxf(t3, b1); t4 = fmaxf(t4, b0);
            CE(t0, t1); CE(t2, t3);
            CE(t1, t2); CE(t3, t4);
            CE(t0, t1); CE(t2, t3);
            CE(t1, t2); CE(t3, t4);
            CE(t0, t1); CE(t2, t3);
        }
        if (es == 0) {
            // Cst row erow = eh*16 + crow maps to patch r0 + eh*64 + mt*16 + crow
            int patch = r0 + (erow >> 4) * 64 + mt * 16 + (erow & 15);
            if (patch < MROWS) {
                float* pp = part + ((size_t)(bg * MROWS + patch) * 2 + nc) * 5;
                pp[0] = t0; pp[1] = t1; pp[2] = t2; pp[3] = t3; pp[4] = t4;
            }
        }
    }
#undef CE
}

// ---------------------------------------------------------------------------
// Merge: one wave per (b,qi,g) = 750 waves. Top-5 of the union of the two
// sorted per-chunk top-5s, mean, wave-reduce over 100 patches, direct store.
// ---------------------------------------------------------------------------
__global__ __launch_bounds__(256) void merge_kernel(const float* __restrict__ part,
                                                    float* __restrict__ out) {
    int w    = (blockIdx.x * 256 + threadIdx.x) >> 6;
    int lane = threadIdx.x & 63;
    if (w >= 750) return;
    int b  = w / 375, r = w % 375;
    int qi = r / 5,   g = r % 5;
    int bg = b * 5 + g;

    float sum = 0.f;
    for (int p = lane; p < HWN; p += 64) {
        int row = qi * HWN + p;
        const float* pp = part + (size_t)(bg * MROWS + row) * 10;
        float t0 = -3.4e38f, t1 = -3.4e38f, t2 = -3.4e38f, t3 = -3.4e38f, t4 = -3.4e38f;
#pragma unroll
        for (int j = 0; j < 10; ++j) {
            float v = pp[j], hi;
            hi = fmaxf(t0, v); v = fminf(t0, v); t0 = hi;
            hi = fmaxf(t1, v); v = fminf(t1, v); t1 = hi;
            hi = fmaxf(t2, v); v = fminf(t2, v); t2 = hi;
            hi = fmaxf(t3, v); v = fminf(t3, v); t3 = hi;
            hi = fmaxf(t4, v); v = fminf(t4, v); t4 = hi;
        }
        sum += (t0 + t1 + t2 + t3 + t4) * 0.2f;
    }
#pragma unroll
    for (int off = 32; off > 0; off >>= 1)
        sum += __shfl_xor(sum, off, 64);
    if (lane == 0) out[w] = sum;        // out[(b*75+qi)*5+g] == out[w]
}

extern "C" void kernel_launch(void* const* d_in, const int* in_sizes, int n_in,
                              void* d_out, int out_size, void* d_ws, size_t ws_size,
                              hipStream_t stream) {
    const float* in1 = (const float*)d_in[0];
    const float* in2 = (const float*)d_in[1];
    float* out = (float*)d_out;

    unsigned short* qbf  = (unsigned short*)d_ws;            // 15000*640 bf16 = 19.2 MB
    unsigned short* sbf  = qbf + (size_t)NQD * CN;           //  5000*640 bf16 =  6.4 MB
    float*          part = (float*)(sbf + (size_t)NSD * CN); // 750000 fp32 = 3 MB

    prep_kernel<<<dim3(NDESC / 4), 256, 0, stream>>>(in1, in2, qbf, sbf);
    mfma_kernel<<<dim3(1200), 512, 0, stream>>>(qbf, sbf, part);   // XCD-clustered
    merge_kernel<<<dim3(188), 256, 0, stream>>>(part, out);        // 750 waves
}